// Round 8
// baseline (237.192 us; speedup 1.0000x reference)
//
#include <hip/hip_runtime.h>

// FinDiffNonUniform: out[n,b] = sum_{s<7} coef[n,s] * y[n + off[n,s], b]
// N=8192, B=4096, S=7, fp32.
//
// Round-9: forced-MLP VGPR loads via inline asm. Evidence: three different
// structures (reg window / one-shot LDS / pipelined LDS ring with counted
// vmcnt) all converge at ~72us = 3.7 TB/s combined, while fill does 6.7 and
// the m13 copy reference does 6.3 on the normal global_load->VGPR path.
// The VGPR path was never really tested: the allocator folded every C-level
// window to 1-2 live buffers (VGPR_Count 36/36/16). Inline-asm
// global_load_dwordx4 with named "=v" outputs is allocator-proof: volatile
// asm is order-fixed vs other volatile asm and its output MUST stay live ->
// 14 loads/wave in flight by construction on the normal load path.
// Consumption: counted s_waitcnt vmcnt(13..0), each wait tied "+v" to the
// row it guards so the (register-only) FMAs are data-dependent on the wait
// and cannot hoist above it (rule-#18 guard). No LDS: occupancy is
// register-limited (~4-5 waves/SIMD at ~110 VGPR), 4096 blocks = 16/CU.
// Decision rule: if VGPR>90 and still ~72us, the R/W-mix is the machine
// limit for this pattern -> roofline.

#define FD_N   8192
#define FD_B   4096
#define FD_S   7
#define FD_R   8
#define HALO   3
#define WIN    (FD_R + 2 * HALO)     // 14
#define NSTRIP (FD_N / FD_R)         // 1024
#define NWG    (NSTRIP * 4)          // 4096 blocks

typedef float v4f __attribute__((ext_vector_type(4)));

// Issue row J's load: dest w##J (4 VGPRs, forced live), saddr = uniform row
// base, voffset = per-lane byte column + J*16384 (row stride in bytes).
#define LOADROW(J)                                                          \
    v4f w##J;                                                               \
    asm volatile("global_load_dwordx4 %0, %1, %2"                           \
                 : "=v"(w##J)                                               \
                 : "v"(voff + (unsigned)((J) * FD_B * 4)), "s"(yrow)        \
                 : "memory");

// Consume row J once vmcnt has drained to VM (loads retire in issue order).
// "+v" tie: FMAs reading w##J become data-dependent on this wait.
#define ROWC(J, VM)                                                         \
    asm volatile("s_waitcnt vmcnt(" #VM ")" : "+v"(w##J)::"memory");        \
    {                                                                       \
        _Pragma("unroll")                                                   \
        for (int r = 0; r < FD_R; ++r) {                                    \
            const int s = (J) - r;                                          \
            if (s >= 0 && s < FD_S) acc[r] += c[r][s] * w##J;               \
        }                                                                   \
    }

__global__ __launch_bounds__(256, 2) void
_FinDiffNonUniform_51608327029442_kernel(const float* __restrict__ y,
                                         const float* __restrict__ coef,
                                         const int*   __restrict__ offs,
                                         float*       __restrict__ out) {
    const int strip = blockIdx.x >> 2;
    const int chunk = blockIdx.x & 3;
    const int n0    = strip * FD_R;
    const int tid   = threadIdx.x;
    const int b     = (chunk << 10) + (tid << 2);   // global column (floats)

    if (strip == 0 || strip == NSTRIP - 1) {
        // ---- edge strips: generic gather with real one-sided offsets ----
#pragma unroll
        for (int r = 0; r < FD_R; ++r) {
            const int n = n0 + r;
            const float* __restrict__ cc = coef + (size_t)n * FD_S;
            const int*   __restrict__ oo = offs + (size_t)n * FD_S;
            v4f acc = (v4f){0.f, 0.f, 0.f, 0.f};
#pragma unroll
            for (int s = 0; s < FD_S; ++s) {
                const v4f v = *reinterpret_cast<const v4f*>(
                    y + (size_t)(n + oo[s]) * FD_B + b);
                acc += cc[s] * v;
            }
            __builtin_nontemporal_store(
                acc, reinterpret_cast<v4f*>(out + (size_t)n * FD_B + b));
        }
        return;
    }

    // ---- interior: centered stencil, 14-row window, forced-MLP loads ----
    // Block-uniform coefficients (SMEM path -> lgkmcnt, disjoint from the
    // asm vmcnt accounting).
    float c[FD_R][FD_S];
#pragma unroll
    for (int r = 0; r < FD_R; ++r)
#pragma unroll
        for (int s = 0; s < FD_S; ++s)
            c[r][s] = coef[(size_t)(n0 + r) * FD_S + s];

    const float*   yrow = y + (size_t)(n0 - HALO) * FD_B;  // uniform (SGPR)
    const unsigned voff = (unsigned)(b * 4);               // per-lane bytes

    // 14 loads issued back-to-back; volatile asm order is fixed; all 14
    // destinations are forced live until their ROWC.
    LOADROW(0)  LOADROW(1)  LOADROW(2)  LOADROW(3)
    LOADROW(4)  LOADROW(5)  LOADROW(6)  LOADROW(7)
    LOADROW(8)  LOADROW(9)  LOADROW(10) LOADROW(11)
    LOADROW(12) LOADROW(13)

    v4f acc[FD_R];
#pragma unroll
    for (int r = 0; r < FD_R; ++r) acc[r] = (v4f){0.f, 0.f, 0.f, 0.f};

    // Consume in arrival order; row J feeds acc[r] with s = J - r in [0,7).
    ROWC(0, 13) ROWC(1, 12) ROWC(2, 11) ROWC(3, 10)
    ROWC(4, 9)  ROWC(5, 8)  ROWC(6, 7)  ROWC(7, 6)
    ROWC(8, 5)  ROWC(9, 4)  ROWC(10, 3) ROWC(11, 2)
    ROWC(12, 1) ROWC(13, 0)

#pragma unroll
    for (int r = 0; r < FD_R; ++r)
        __builtin_nontemporal_store(
            acc[r], reinterpret_cast<v4f*>(out + (size_t)(n0 + r) * FD_B + b));
}

extern "C" void kernel_launch(void* const* d_in, const int* in_sizes, int n_in,
                              void* d_out, int out_size, void* d_ws, size_t ws_size,
                              hipStream_t stream) {
    const float* y    = (const float*)d_in[0];
    const float* coef = (const float*)d_in[1];
    const int*   offs = (const int*)d_in[2];
    float*       out  = (float*)d_out;

    _FinDiffNonUniform_51608327029442_kernel<<<NWG, 256, 0, stream>>>(y, coef, offs, out);
}